// Round 5
// baseline (4307.656 us; speedup 1.0000x reference)
//
#include <hip/hip_runtime.h>
#include <cstdint>
#include <cstddef>

#define TPB 256

// ---------------- index-building kernels ----------------

static __global__ void kscatter(int* __restrict__ grid, const int* __restrict__ coords,
                                int N, int S) {
    int i = blockIdx.x * blockDim.x + threadIdx.x;
    if (i >= N) return;
    int x = coords[3 * i], y = coords[3 * i + 1], z = coords[3 * i + 2];
    grid[(x * S + y) * S + z] = i;
}

// invalid neighbors are remapped to zr (the zero-row index)
static __global__ void knbr27(int* __restrict__ nbr, const int* __restrict__ coords,
                              const int* __restrict__ grid, int N, int S, int zr) {
    int t = blockIdx.x * blockDim.x + threadIdx.x;
    if (t >= N * 27) return;
    int n = t / 27, k = t - 27 * n;
    int x = coords[3 * n]     + (k / 9) - 1;
    int y = coords[3 * n + 1] + ((k / 3) % 3) - 1;
    int z = coords[3 * n + 2] + (k % 3) - 1;
    int v = -1;
    if ((unsigned)x < (unsigned)S && (unsigned)y < (unsigned)S && (unsigned)z < (unsigned)S)
        v = grid[(x * S + y) * S + z];
    nbr[t] = (v < 0) ? zr : v;
}

static __global__ void kdown8(int* __restrict__ dn, const int* __restrict__ coords,
                              const int* __restrict__ grid, int M, int S_f, int zr) {
    int t = blockIdx.x * blockDim.x + threadIdx.x;
    if (t >= M * 8) return;
    int n = t >> 3, k = t & 7;
    int x = coords[3 * n] * 2     + ((k >> 2) & 1);
    int y = coords[3 * n + 1] * 2 + ((k >> 1) & 1);
    int z = coords[3 * n + 2] * 2 + (k & 1);
    int v = grid[(x * S_f + y) * S_f + z];
    dn[t] = (v < 0) ? zr : v;
}

static __global__ void kup(int* __restrict__ up, const int* __restrict__ cf,
                           const int* __restrict__ gc, int N, int Sc) {
    int n = blockIdx.x * blockDim.x + threadIdx.x;
    if (n >= N) return;
    int x = cf[3 * n] >> 2, y = cf[3 * n + 1] >> 2, z = cf[3 * n + 2] >> 2;
    up[n] = gc[(x * Sc + y) * Sc + z];       // parent always exists
}

// W[K][A][B] -> Wt[K][B][A]
static __global__ void ktrans(float* __restrict__ Wt, const float* __restrict__ W,
                              int K, int A, int B) {
    int t = blockIdx.x * blockDim.x + threadIdx.x;
    if (t >= K * A * B) return;
    int a = t % A, b = (t / A) % B, k = t / (A * B);
    Wt[t] = W[(k * A + a) * B + b];
}

static __global__ void kzrow(float* __restrict__ p, int n) {
    int i = blockIdx.x * blockDim.x + threadIdx.x;
    if (i < n) p[i] = 0.0f;
}

// ---------------- BN stats + fused BN-ReLU pass ----------------

static __global__ void kstats(double* __restrict__ st, const float* __restrict__ x,
                              int N, int C) {
    extern __shared__ double sh[];          // 2 * 4*C doubles
    int tid = threadIdx.x;
    int c = tid % C, rl = tid / C;
    double s = 0.0, q = 0.0;
    int base = blockIdx.x * 256 + rl * 64;
    for (int it = 0; it < 64; it++) {
        int r = base + it;
        if (r < N) {
            double v = (double)x[(size_t)r * C + c];
            s += v;
            q = fma(v, v, q);
        }
    }
    double* ss = sh;
    double* sq = sh + 4 * C;
    ss[tid] = s; sq[tid] = q;
    __syncthreads();
    if (tid < C) {
        double S = ss[tid] + ss[tid + C] + ss[tid + 2 * C] + ss[tid + 3 * C];
        double Q = sq[tid] + sq[tid + C] + sq[tid + 2 * C] + sq[tid + 3 * C];
        atomicAdd(&st[tid], S);
        atomicAdd(&st[80 + tid], Q);
    }
}

// y has N+1 rows; row N is the zero row. float4 vectorized.
static __global__ void kbnrelu(float4* __restrict__ y, const float4* __restrict__ x,
                               const double* __restrict__ st, const float* __restrict__ g,
                               const float* __restrict__ b, int N, int C) {
    __shared__ float sc[80], bh[80];
    int tid = threadIdx.x;
    if (tid < C) {
        double invN = 1.0 / (double)N;
        double mu = st[tid] * invN;
        double var = st[80 + tid] * invN - mu * mu;
        float s = g[tid] * rsqrtf((float)var + 1e-4f);
        sc[tid] = s;
        bh[tid] = b[tid] - (float)mu * s;
    }
    __syncthreads();
    int C4 = C >> 2;
    int quads = (N + 1) * C4;
    int t = blockIdx.x * blockDim.x + tid;
    if (t >= quads) return;
    int n = t / C4;
    if (n >= N) { y[t] = make_float4(0.f, 0.f, 0.f, 0.f); return; }
    int c0 = (t - n * C4) * 4;
    float4 q = x[t];
    float4 r;
    r.x = fmaxf(fmaf(q.x, sc[c0 + 0], bh[c0 + 0]), 0.f);
    r.y = fmaxf(fmaf(q.y, sc[c0 + 1], bh[c0 + 1]), 0.f);
    r.z = fmaxf(fmaf(q.z, sc[c0 + 2], bh[c0 + 2]), 0.f);
    r.w = fmaxf(fmaf(q.w, sc[c0 + 3], bh[c0 + 3]), 0.f);
    y[t] = r;
}

// ---------------- pipelined LDS-staged tile conv ----------------
// out[n,b] (+= res) = sum_k sum_a feat[nbr[n,k], a] * Wt[k, b, a]
// Register-prefetch of tap k+1 (feature rows + weight tile) overlaps the
// global latency with tap k's compute. LDS double-buffered when it fits
// <=50 KB (1 barrier/tap), else single-buffered (2 barriers/tap).
// KG>1: taps split across blockIdx.y groups, fp32 atomicAdd accumulate
// (out pre-zeroed by host if res==null; if res!=null then res==out).

template <int A, int B, int TAPS, int TR, int TX, int KG, bool ADD>
__launch_bounds__(256)
static __global__ void kconv3(float* __restrict__ out, const float* __restrict__ feat,
                              const int* __restrict__ nbr, const float* __restrict__ Wt,
                              const float* __restrict__ res, int N, int zr) {
    constexpr int A4 = A / 4;
    constexpr int PITCH = A + 4;              // breaks pow-2 bank strides
    constexpr int TY = 256 / TX;
    constexpr int RT = TR / TY;
    constexpr int CT = B / TX;
    constexpr int GQ = TR * A4;
    constexpr int WQ = B * A4;
    constexpr int GPT = (GQ + 255) / 256;
    constexpr int WPT = (WQ + 255) / 256;
    constexpr int KPG = (TAPS + KG - 1) / KG;
    constexpr int NBUF = ((2 * (TR + B) * PITCH * 4) <= 50 * 1024) ? 2 : 1;

    __shared__ __attribute__((aligned(16))) float gs[NBUF][TR * PITCH];
    __shared__ __attribute__((aligned(16))) float wsh[NBUF][B * PITCH];

    const int tid = threadIdx.x;
    const int tx = tid % TX, ty = tid / TX;
    const int row0 = blockIdx.x * TR;
    const int k0 = blockIdx.y * KPG;
    const int k1 = (k0 + KPG < TAPS) ? (k0 + KPG) : TAPS;
    const float4* f4 = (const float4*)feat;

    float4 gpre[GPT], wpre[WPT];

    auto loadtap = [&](int k) {
        const float4* wk = (const float4*)(Wt + (size_t)k * B * A);
#pragma unroll
        for (int it = 0; it < WPT; it++) {
            int idx = tid + it * 256;
            if (WQ % 256 == 0 || idx < WQ) wpre[it] = wk[idx];
        }
#pragma unroll
        for (int it = 0; it < GPT; it++) {
            int idx = tid + it * 256;
            if (GQ % 256 == 0 || idx < GQ) {
                int rr = idx / A4, sg = idx - rr * A4;
                int r = row0 + rr;
                int id = (r < N) ? nbr[(size_t)r * TAPS + k] : zr;
                gpre[it] = f4[(size_t)id * A4 + sg];
            }
        }
    };
    auto storetap = [&](int buf) {
#pragma unroll
        for (int it = 0; it < WPT; it++) {
            int idx = tid + it * 256;
            if (WQ % 256 == 0 || idx < WQ) {
                int br = idx / A4, sg = idx - br * A4;
                *(float4*)&wsh[buf][br * PITCH + sg * 4] = wpre[it];
            }
        }
#pragma unroll
        for (int it = 0; it < GPT; it++) {
            int idx = tid + it * 256;
            if (GQ % 256 == 0 || idx < GQ) {
                int rr = idx / A4, sg = idx - rr * A4;
                *(float4*)&gs[buf][rr * PITCH + sg * 4] = gpre[it];
            }
        }
    };

    float acc[RT][CT];
#pragma unroll
    for (int i = 0; i < RT; i++) {
        int r = row0 + ty + TY * i;
#pragma unroll
        for (int j = 0; j < CT; j++)
            acc[i][j] = (ADD && KG == 1 && r < N) ? res[(size_t)r * B + tx + TX * j] : 0.0f;
    }

    loadtap(k0);
    for (int k = k0; k < k1; k++) {
        int buf = (NBUF == 2) ? ((k - k0) & 1) : 0;
        if (NBUF == 1 && k > k0) __syncthreads();   // prior compute must drain
        storetap(buf);
        __syncthreads();
        if (k + 1 < k1) loadtap(k + 1);             // prefetch overlaps compute
#pragma unroll
        for (int ac = 0; ac < A4; ac++) {
            float4 w[CT];
#pragma unroll
            for (int j = 0; j < CT; j++)
                w[j] = *(const float4*)&wsh[buf][(tx + TX * j) * PITCH + ac * 4];
            float4 g[RT];
#pragma unroll
            for (int i = 0; i < RT; i++)
                g[i] = *(const float4*)&gs[buf][(ty + TY * i) * PITCH + ac * 4];
#pragma unroll
            for (int i = 0; i < RT; i++)
#pragma unroll
                for (int j = 0; j < CT; j++) {
                    acc[i][j] = fmaf(g[i].x, w[j].x, acc[i][j]);
                    acc[i][j] = fmaf(g[i].y, w[j].y, acc[i][j]);
                    acc[i][j] = fmaf(g[i].z, w[j].z, acc[i][j]);
                    acc[i][j] = fmaf(g[i].w, w[j].w, acc[i][j]);
                }
        }
    }

#pragma unroll
    for (int i = 0; i < RT; i++) {
        int r = row0 + ty + TY * i;
        if (r < N) {
#pragma unroll
            for (int j = 0; j < CT; j++) {
                if (KG > 1) atomicAdd(&out[(size_t)r * B + tx + TX * j], acc[i][j]);
                else out[(size_t)r * B + tx + TX * j] = acc[i][j];
            }
        }
    }
}

// input layer: A=1, B=16; vectorized over b-quads
static __global__ void kconv_in(float* __restrict__ out, const float* __restrict__ f,
                                const int* __restrict__ nbr, const float* __restrict__ W,
                                int N, int zr) {
    int t = blockIdx.x * blockDim.x + threadIdx.x;
    if (t >= N * 4) return;
    int n = t >> 2, bq = t & 3;
    float4 acc = make_float4(0.f, 0.f, 0.f, 0.f);
    const float4* W4 = (const float4*)W;
    for (int k = 0; k < 27; k++) {
        int id = nbr[n * 27 + k];
        if (id == zr) continue;
        float v = f[id];
        float4 w = W4[k * 4 + bq];
        acc.x = fmaf(v, w.x, acc.x);
        acc.y = fmaf(v, w.y, acc.y);
        acc.z = fmaf(v, w.z, acc.z);
        acc.w = fmaf(v, w.w, acc.w);
    }
    ((float4*)out)[n * 4 + bq] = acc;
}

// ---------------- heads / epilogue ----------------

static __global__ void kscores(float* __restrict__ sc, const float* __restrict__ x,
                               const float* __restrict__ w, int N, int C) {
    int n = blockIdx.x * blockDim.x + threadIdx.x;
    if (n >= N) return;
    float s0 = 0.0f, s1 = 0.0f;
    const float* xr = x + (size_t)n * C;
    for (int c = 0; c < C; c++) {
        float v = xr[c];
        s0 = fmaf(v, w[2 * c], s0);
        s1 = fmaf(v, w[2 * c + 1], s1);
    }
    sc[2 * n] = s0;
    sc[2 * n + 1] = s1;
}

// y has N+1 rows (row N zeroed). float4 vectorized.
static __global__ void kmulatt(float4* __restrict__ y, const float4* __restrict__ fmap,
                               const int* __restrict__ up, const float* __restrict__ sc,
                               int N, int C4) {
    int t = blockIdx.x * blockDim.x + threadIdx.x;
    if (t >= (N + 1) * C4) return;
    int n = t / C4;
    if (n >= N) { y[t] = make_float4(0.f, 0.f, 0.f, 0.f); return; }
    int p = up[n];
    float att = (sc[2 * p + 1] > sc[2 * p]) ? 1.0f : 0.0f;
    float4 q = fmap[t];
    y[t] = make_float4(q.x * att, q.y * att, q.z * att, q.w * att);
}

static __global__ void kout0(float* __restrict__ out, const float* __restrict__ z,
                             const float* __restrict__ pw, const float* __restrict__ sw,
                             int N) {
    int n = blockIdx.x * blockDim.x + threadIdx.x;
    if (n >= N) return;
    float o0 = 0, o1 = 0, o2 = 0, o3 = 0, o4 = 0;
    const float* zr = z + (size_t)n * 16;
#pragma unroll
    for (int c = 0; c < 16; c++) {
        float v = zr[c];
        o0 = fmaf(v, pw[3 * c], o0);
        o1 = fmaf(v, pw[3 * c + 1], o1);
        o2 = fmaf(v, pw[3 * c + 2], o2);
        o3 = fmaf(v, sw[2 * c], o3);
        o4 = fmaf(v, sw[2 * c + 1], o4);
    }
    float* r = out + (size_t)n * 5;
    r[0] = o0; r[1] = o1; r[2] = o2; r[3] = o3; r[4] = o4;
}

static __global__ void koutc(float* __restrict__ out, const int* __restrict__ coords,
                             const float* __restrict__ sc, int N) {
    int n = blockIdx.x * blockDim.x + threadIdx.x;
    if (n >= N) return;
    float* r = out + (size_t)n * 5;
    r[0] = (float)coords[3 * n];
    r[1] = (float)coords[3 * n + 1];
    r[2] = (float)coords[3 * n + 2];
    r[3] = sc[2 * n];
    r[4] = sc[2 * n + 1];
}

// ---------------- host-side helpers ----------------

static inline int cdiv(long a, int b) { return (int)((a + b - 1) / b); }

static void conv(hipStream_t s, float* out, const float* feat, const int* nbr,
                 const float* Wt, const float* res, int N, int A, int B, int TAPS, int zr) {
#define CASE(AA, BB, TT, TRR, TXX, KGG)                                                    \
    else if (A == AA && B == BB && TAPS == TT) {                                           \
        if (KGG > 1 && !res) hipMemsetAsync(out, 0, (size_t)N * BB * 4, s);                \
        dim3 g(cdiv(N, TRR), KGG), blk(256);                                               \
        if (res) kconv3<AA, BB, TT, TRR, TXX, KGG, true><<<g, blk, 0, s>>>(out, feat, nbr, Wt, res, N, zr); \
        else     kconv3<AA, BB, TT, TRR, TXX, KGG, false><<<g, blk, 0, s>>>(out, feat, nbr, Wt, nullptr, N, zr); \
    }
    if (false) {}
    CASE(16, 16, 27, 128, 8, 1)   // L0 sub + ppn3 (N~100k)
    CASE(32, 32, 27, 128, 8, 1)   // L1 sub (N~92k)
    CASE(48, 48, 27, 64, 8, 1)    // L2 sub + ppn2 (N~63k)
    CASE(64, 64, 27, 32, 16, 2)   // L3 sub (N~14k) -> 2 tap groups
    CASE(80, 80, 27, 32, 16, 9)   // ppn1 @ L4 (N~1.7k) -> 9 tap groups
    CASE(16, 32, 8, 128, 8, 1)    // down0
    CASE(32, 48, 8, 128, 8, 1)    // down1
    CASE(48, 64, 8, 32, 16, 1)    // down2
    CASE(64, 80, 8, 32, 16, 4)    // down3 -> 4 tap groups
#undef CASE
}

static void bnapply(hipStream_t s, float* out, const float* x, double* st,
                    const float* g, const float* b, int N, int C) {
    kstats<<<cdiv(N, 256), 4 * C, 8 * C * 2 * sizeof(double), s>>>(st, x, N, C);
    int quads = (N + 1) * (C / 4);
    kbnrelu<<<cdiv(quads, 256), 256, 0, s>>>((float4*)out, (const float4*)x, st, g, b, N, C);
}

extern "C" void kernel_launch(void* const* d_in, const int* in_sizes, int n_in,
                              void* d_out, int out_size, void* d_ws, size_t ws_size,
                              hipStream_t stream) {
    (void)n_in; (void)out_size; (void)ws_size;
    const int SL[5] = {192, 96, 48, 24, 12};
    const int C[5] = {16, 32, 48, 64, 80};
    int N[5];
    const int* coords[5];
    for (int l = 0; l < 5; l++) { N[l] = in_sizes[l] / 3; coords[l] = (const int*)d_in[l]; }
    const float* features = (const float*)d_in[5];
    const float* w_in = (const float*)d_in[6];
    const float *blk_w[4], *blk_g[4], *blk_b[4], *dn_g[4], *dn_b[4], *dn_w[4];
    for (int i = 0; i < 4; i++) {
        blk_w[i] = (const float*)d_in[7 + 6 * i];
        blk_g[i] = (const float*)d_in[8 + 6 * i];
        blk_b[i] = (const float*)d_in[9 + 6 * i];
        dn_g[i] = (const float*)d_in[10 + 6 * i];
        dn_b[i] = (const float*)d_in[11 + 6 * i];
        dn_w[i] = (const float*)d_in[12 + 6 * i];
    }
    const float* ppn1_w  = (const float*)d_in[31];
    const float* ppn1_sw = (const float*)d_in[32];
    const float* ppn2_w  = (const float*)d_in[33];
    const float* ppn2_sw = (const float*)d_in[34];
    const float* ppn3_w  = (const float*)d_in[35];
    const float* ppn3_pw = (const float*)d_in[36];
    const float* ppn3_sw = (const float*)d_in[37];
    float* dout = (float*)d_out;

    // ---- workspace layout ----
    char* ws = (char*)d_ws;
    size_t off = 0;
    auto alloc = [&](size_t bytes) -> char* {
        off = (off + 255) & ~(size_t)255;
        char* p = ws + off;
        off += bytes;
        return p;
    };
    int* nbr[5];
    for (int l = 0; l < 5; l++) nbr[l] = (int*)alloc((size_t)N[l] * 27 * 4);
    int* down8[4];
    for (int i = 0; i < 4; i++) down8[i] = (int*)alloc((size_t)N[i + 1] * 8 * 4);
    int* up1 = (int*)alloc((size_t)N[2] * 4);
    int* up2 = (int*)alloc((size_t)N[0] * 4);
    double* stats = (double*)alloc(26 * 160 * sizeof(double));
    float* blkWt[4];
    float* dnWt[4];
    for (int i = 0; i < 4; i++) {
        blkWt[i] = (float*)alloc((size_t)108 * C[i] * C[i] * 4);
        dnWt[i] = (float*)alloc((size_t)8 * C[i] * C[i + 1] * 4);
    }
    float* p1Wt = (float*)alloc((size_t)27 * 80 * 80 * 4);
    float* p2Wt = (float*)alloc((size_t)27 * 48 * 48 * 4);
    float* p3Wt = (float*)alloc((size_t)27 * 16 * 16 * 4);
    float* fmap0 = (float*)alloc((size_t)N[0] * 16 * 4);
    float* fmap2 = (float*)alloc((size_t)N[2] * 48 * 4);
    float* sc1 = (float*)alloc((size_t)N[4] * 2 * 4);
    float* sc2 = (float*)alloc((size_t)N[2] * 2 * 4);

    // transient region: grids (phase 1) alias the 3 rotating feature buffers (phase 2)
    size_t BIG = 0;
    for (int l = 0; l < 5; l++) {
        size_t s = (size_t)(N[l] + 1) * C[l] * 4;
        if (s > BIG) BIG = s;
    }
    BIG = (BIG + 255) & ~(size_t)255;
    off = (off + 255) & ~(size_t)255;
    size_t trans = off;
    int* grid[5];
    size_t gtot = 0;
    for (int l = 0; l < 5; l++) {
        grid[l] = (int*)(ws + trans + gtot);
        gtot += (size_t)SL[l] * SL[l] * SL[l] * 4;
    }
    float* B0 = (float*)(ws + trans);
    float* B1 = (float*)(ws + trans + BIG);
    float* B2 = (float*)(ws + trans + 2 * BIG);

    // ---- phase 1: index structures + weight transposes + stats zero ----
    hipMemsetAsync(ws + trans, 0xFF, gtot, stream);  // all grids = -1
    hipMemsetAsync(stats, 0, 26 * 160 * sizeof(double), stream);
    for (int l = 0; l < 5; l++)
        kscatter<<<cdiv(N[l], TPB), TPB, 0, stream>>>(grid[l], coords[l], N[l], SL[l]);
    for (int l = 0; l < 5; l++)
        knbr27<<<cdiv((long)N[l] * 27, TPB), TPB, 0, stream>>>(nbr[l], coords[l], grid[l], N[l], SL[l], N[l]);
    for (int i = 0; i < 4; i++)
        kdown8<<<cdiv((long)N[i + 1] * 8, TPB), TPB, 0, stream>>>(down8[i], coords[i + 1], grid[i], N[i + 1], SL[i], N[i]);
    kup<<<cdiv(N[2], TPB), TPB, 0, stream>>>(up1, coords[2], grid[4], N[2], 12);
    kup<<<cdiv(N[0], TPB), TPB, 0, stream>>>(up2, coords[0], grid[2], N[0], 48);
    for (int i = 0; i < 4; i++) {
        int n1 = 108 * C[i] * C[i];
        ktrans<<<cdiv(n1, TPB), TPB, 0, stream>>>(blkWt[i], blk_w[i], 108, C[i], C[i]);
        int n2 = 8 * C[i] * C[i + 1];
        ktrans<<<cdiv(n2, TPB), TPB, 0, stream>>>(dnWt[i], dn_w[i], 8, C[i], C[i + 1]);
    }
    ktrans<<<cdiv(27 * 6400, TPB), TPB, 0, stream>>>(p1Wt, ppn1_w, 27, 80, 80);
    ktrans<<<cdiv(27 * 2304, TPB), TPB, 0, stream>>>(p2Wt, ppn2_w, 27, 48, 48);
    ktrans<<<cdiv(27 * 256, TPB), TPB, 0, stream>>>(p3Wt, ppn3_w, 27, 16, 16);

    // ---- phase 2: network (grids dead; B0/B1/B2 alias that memory) ----
    int slot = 0;
    auto st = [&]() { return stats + 160 * (slot++); };

    float* curX = B0;
    kconv_in<<<cdiv((long)N[0] * 4, TPB), TPB, 0, stream>>>(curX, features, nbr[0], w_in, N[0], N[0]);
    hipMemcpyAsync(fmap0, curX, (size_t)N[0] * 16 * 4, hipMemcpyDeviceToDevice, stream);

    auto others = [&](float* cur, float*& t1, float*& t2) {
        if (cur == B0) { t1 = B1; t2 = B2; }
        else if (cur == B1) { t1 = B0; t2 = B2; }
        else { t1 = B0; t2 = B1; }
    };

    for (int i = 0; i < 4; i++) {
        int Ni = N[i], Ci = C[i];
        float *T1, *T2;
        others(curX, T1, T2);
        for (int r = 0; r < 2; r++) {
            const float* w0 = blkWt[i] + (size_t)(2 * r) * 27 * Ci * Ci;
            const float* w1 = blkWt[i] + (size_t)(2 * r + 1) * 27 * Ci * Ci;
            bnapply(stream, T1, curX, st(), blk_g[i] + (2 * r) * Ci, blk_b[i] + (2 * r) * Ci, Ni, Ci);
            conv(stream, T2, T1, nbr[i], w0, nullptr, Ni, Ci, Ci, 27, Ni);
            bnapply(stream, T1, T2, st(), blk_g[i] + (2 * r + 1) * Ci, blk_b[i] + (2 * r + 1) * Ci, Ni, Ci);
            conv(stream, curX, T1, nbr[i], w1, curX, Ni, Ci, Ci, 27, Ni);   // fused residual (out==res)
        }
        bnapply(stream, T1, curX, st(), dn_g[i], dn_b[i], Ni, Ci);
        conv(stream, T2, T1, down8[i], dnWt[i], nullptr, N[i + 1], Ci, C[i + 1], 8, Ni);
        if (i == 1)
            hipMemcpyAsync(fmap2, T2, (size_t)N[2] * 48 * 4, hipMemcpyDeviceToDevice, stream);
        curX = T2;
    }

    // ---- heads ----
    float *T1, *T2;
    others(curX, T1, T2);
    // curX = level-4 features; append zero row for ppn1 gather
    kzrow<<<1, 128, 0, stream>>>(curX + (size_t)N[4] * 80, 80);
    conv(stream, T1, curX, nbr[4], p1Wt, nullptr, N[4], 80, 80, 27, N[4]);
    kscores<<<cdiv(N[4], TPB), TPB, 0, stream>>>(sc1, T1, ppn1_sw, N[4], 80);
    koutc<<<cdiv(N[4], TPB), TPB, 0, stream>>>(dout + (size_t)N[0] * 5, coords[4], sc1, N[4]);
    // ppn2 @ level 2
    kmulatt<<<cdiv((long)(N[2] + 1) * 12, TPB), TPB, 0, stream>>>((float4*)T2, (const float4*)fmap2, up1, sc1, N[2], 12);
    conv(stream, curX, T2, nbr[2], p2Wt, nullptr, N[2], 48, 48, 27, N[2]);
    kscores<<<cdiv(N[2], TPB), TPB, 0, stream>>>(sc2, curX, ppn2_sw, N[2], 48);
    koutc<<<cdiv(N[2], TPB), TPB, 0, stream>>>(dout + (size_t)(N[0] + N[4]) * 5, coords[2], sc2, N[2]);
    // ppn3 @ level 0
    kmulatt<<<cdiv((long)(N[0] + 1) * 4, TPB), TPB, 0, stream>>>((float4*)T1, (const float4*)fmap0, up2, sc2, N[0], 4);
    conv(stream, T2, T1, nbr[0], p3Wt, nullptr, N[0], 16, 16, 27, N[0]);
    kout0<<<cdiv(N[0], TPB), TPB, 0, stream>>>(dout, T2, ppn3_pw, ppn3_sw, N[0]);
}

// Round 6
// 2926.948 us; speedup vs baseline: 1.4717x; 1.4717x over previous
//
#include <hip/hip_runtime.h>
#include <cstdint>
#include <cstddef>

#define TPB 256

// ---------------- index-building kernels ----------------

static __global__ void kscatter(int* __restrict__ grid, const int* __restrict__ coords,
                                int N, int S) {
    int i = blockIdx.x * blockDim.x + threadIdx.x;
    if (i >= N) return;
    int x = coords[3 * i], y = coords[3 * i + 1], z = coords[3 * i + 2];
    grid[(x * S + y) * S + z] = i;
}

// invalid neighbors are remapped to zr (the zero-row index)
static __global__ void knbr27(int* __restrict__ nbr, const int* __restrict__ coords,
                              const int* __restrict__ grid, int N, int S, int zr) {
    int t = blockIdx.x * blockDim.x + threadIdx.x;
    if (t >= N * 27) return;
    int n = t / 27, k = t - 27 * n;
    int x = coords[3 * n]     + (k / 9) - 1;
    int y = coords[3 * n + 1] + ((k / 3) % 3) - 1;
    int z = coords[3 * n + 2] + (k % 3) - 1;
    int v = -1;
    if ((unsigned)x < (unsigned)S && (unsigned)y < (unsigned)S && (unsigned)z < (unsigned)S)
        v = grid[(x * S + y) * S + z];
    nbr[t] = (v < 0) ? zr : v;
}

static __global__ void kdown8(int* __restrict__ dn, const int* __restrict__ coords,
                              const int* __restrict__ grid, int M, int S_f, int zr) {
    int t = blockIdx.x * blockDim.x + threadIdx.x;
    if (t >= M * 8) return;
    int n = t >> 3, k = t & 7;
    int x = coords[3 * n] * 2     + ((k >> 2) & 1);
    int y = coords[3 * n + 1] * 2 + ((k >> 1) & 1);
    int z = coords[3 * n + 2] * 2 + (k & 1);
    int v = grid[(x * S_f + y) * S_f + z];
    dn[t] = (v < 0) ? zr : v;
}

static __global__ void kup(int* __restrict__ up, const int* __restrict__ cf,
                           const int* __restrict__ gc, int N, int Sc) {
    int n = blockIdx.x * blockDim.x + threadIdx.x;
    if (n >= N) return;
    int x = cf[3 * n] >> 2, y = cf[3 * n + 1] >> 2, z = cf[3 * n + 2] >> 2;
    up[n] = gc[(x * Sc + y) * Sc + z];       // parent always exists
}

// W[K][A][B] -> Wt[K][B][A]
static __global__ void ktrans(float* __restrict__ Wt, const float* __restrict__ W,
                              int K, int A, int B) {
    int t = blockIdx.x * blockDim.x + threadIdx.x;
    if (t >= K * A * B) return;
    int a = t % A, b = (t / A) % B, k = t / (A * B);
    Wt[t] = W[(k * A + a) * B + b];
}

static __global__ void kzrow(float* __restrict__ p, int n) {
    int i = blockIdx.x * blockDim.x + threadIdx.x;
    if (i < n) p[i] = 0.0f;
}

// ---------------- BN stats + fused BN-ReLU pass ----------------

static __global__ void kstats(double* __restrict__ st, const float* __restrict__ x,
                              int N, int C) {
    extern __shared__ double sh[];          // 2 * 4*C doubles
    int tid = threadIdx.x;
    int c = tid % C, rl = tid / C;
    double s = 0.0, q = 0.0;
    int base = blockIdx.x * 256 + rl * 64;
    for (int it = 0; it < 64; it++) {
        int r = base + it;
        if (r < N) {
            double v = (double)x[(size_t)r * C + c];
            s += v;
            q = fma(v, v, q);
        }
    }
    double* ss = sh;
    double* sq = sh + 4 * C;
    ss[tid] = s; sq[tid] = q;
    __syncthreads();
    if (tid < C) {
        double S = ss[tid] + ss[tid + C] + ss[tid + 2 * C] + ss[tid + 3 * C];
        double Q = sq[tid] + sq[tid + C] + sq[tid + 2 * C] + sq[tid + 3 * C];
        atomicAdd(&st[tid], S);
        atomicAdd(&st[80 + tid], Q);
    }
}

// y has N+1 rows; row N is the zero row. float4 vectorized.
static __global__ void kbnrelu(float4* __restrict__ y, const float4* __restrict__ x,
                               const double* __restrict__ st, const float* __restrict__ g,
                               const float* __restrict__ b, int N, int C) {
    __shared__ float sc[80], bh[80];
    int tid = threadIdx.x;
    if (tid < C) {
        double invN = 1.0 / (double)N;
        double mu = st[tid] * invN;
        double var = st[80 + tid] * invN - mu * mu;
        float s = g[tid] * rsqrtf((float)var + 1e-4f);
        sc[tid] = s;
        bh[tid] = b[tid] - (float)mu * s;
    }
    __syncthreads();
    int C4 = C >> 2;
    int quads = (N + 1) * C4;
    int t = blockIdx.x * blockDim.x + tid;
    if (t >= quads) return;
    int n = t / C4;
    if (n >= N) { y[t] = make_float4(0.f, 0.f, 0.f, 0.f); return; }
    int c0 = (t - n * C4) * 4;
    float4 q = x[t];
    float4 r;
    r.x = fmaxf(fmaf(q.x, sc[c0 + 0], bh[c0 + 0]), 0.f);
    r.y = fmaxf(fmaf(q.y, sc[c0 + 1], bh[c0 + 1]), 0.f);
    r.z = fmaxf(fmaf(q.z, sc[c0 + 2], bh[c0 + 2]), 0.f);
    r.w = fmaxf(fmaf(q.w, sc[c0 + 3], bh[c0 + 3]), 0.f);
    y[t] = r;
}

// ---------------- LDS-staged tile conv (round-4 structure + KG tap split) ----
// out[n,b] (+= res) = sum_k sum_a feat[nbr[n,k], a] * Wt[k, b, a]
// Per k-tap: block cooperatively stages TR feature rows + the B x A weight
// tile into LDS (pitch A+4, conflict-free), then computes a TR x B tile.
// No register prefetch (round-5 scratch-spill lesson).
// KG>1: taps split across blockIdx.y groups, fp32 atomicAdd accumulate.
// For ADD with KG>1, caller guarantees out==res (accumulate onto resident x);
// for !ADD with KG>1, caller pre-zeroes out.

template <int A, int B, int TAPS, int TR, int TX, int KG, bool ADD>
__launch_bounds__(256)
static __global__ void kconv2(float* __restrict__ out, const float* __restrict__ feat,
                              const int* __restrict__ nbr, const float* __restrict__ Wt,
                              const float* __restrict__ res, int N, int zr) {
    constexpr int A4 = A / 4;
    constexpr int PITCH = A + 4;              // floats; breaks pow-2 bank strides
    constexpr int TY = 256 / TX;
    constexpr int RT = TR / TY;
    constexpr int CT = B / TX;
    constexpr int GQ = TR * A4;               // gather float4s per tap
    constexpr int WQ = B * A4;                // weight float4s per tap
    constexpr int KPG = (TAPS + KG - 1) / KG;

    __shared__ __attribute__((aligned(16))) float gs[TR * PITCH];
    __shared__ __attribute__((aligned(16))) float wsh[B * PITCH];

    const int tid = threadIdx.x;
    const int tx = tid % TX, ty = tid / TX;
    const int row0 = blockIdx.x * TR;
    const int k0 = (KG > 1) ? blockIdx.y * KPG : 0;
    const int k1 = (KG > 1) ? ((k0 + KPG < TAPS) ? k0 + KPG : TAPS) : TAPS;
    const float4* f4 = (const float4*)feat;

    float acc[RT][CT];
#pragma unroll
    for (int i = 0; i < RT; i++) {
        int r = row0 + ty + TY * i;
#pragma unroll
        for (int j = 0; j < CT; j++)
            acc[i][j] = (ADD && KG == 1 && r < N) ? res[(size_t)r * B + tx + TX * j] : 0.0f;
    }

    for (int k = k0; k < k1; k++) {
        __syncthreads();                      // prev-iter LDS reads done
        // stage weight tile Wt[k] (B x A, row-major) into wsh
        const float4* wk = (const float4*)(Wt + (size_t)k * B * A);
#pragma unroll
        for (int it = 0; it < (WQ + 255) / 256; it++) {
            int idx = tid + it * 256;
            if (WQ % 256 == 0 || idx < WQ) {
                int br = idx / A4, seg = idx - br * A4;
                *(float4*)&wsh[br * PITCH + seg * 4] = wk[idx];
            }
        }
        // gather TR feature rows into gs
#pragma unroll
        for (int it = 0; it < (GQ + 255) / 256; it++) {
            int idx = tid + it * 256;
            if (GQ % 256 == 0 || idx < GQ) {
                int rr = idx / A4, seg = idx - rr * A4;
                int r = row0 + rr;
                int id = (r < N) ? nbr[(size_t)r * TAPS + k] : zr;
                *(float4*)&gs[rr * PITCH + seg * 4] = f4[(size_t)id * A4 + seg];
            }
        }
        __syncthreads();
        // compute from LDS
#pragma unroll
        for (int ac = 0; ac < A4; ac++) {
            float4 w[CT];
#pragma unroll
            for (int j = 0; j < CT; j++)
                w[j] = *(const float4*)&wsh[(tx + TX * j) * PITCH + ac * 4];
            float4 g[RT];
#pragma unroll
            for (int i = 0; i < RT; i++)
                g[i] = *(const float4*)&gs[(ty + TY * i) * PITCH + ac * 4];
#pragma unroll
            for (int i = 0; i < RT; i++)
#pragma unroll
                for (int j = 0; j < CT; j++) {
                    acc[i][j] = fmaf(g[i].x, w[j].x, acc[i][j]);
                    acc[i][j] = fmaf(g[i].y, w[j].y, acc[i][j]);
                    acc[i][j] = fmaf(g[i].z, w[j].z, acc[i][j]);
                    acc[i][j] = fmaf(g[i].w, w[j].w, acc[i][j]);
                }
        }
    }

#pragma unroll
    for (int i = 0; i < RT; i++) {
        int r = row0 + ty + TY * i;
        if (r < N) {
#pragma unroll
            for (int j = 0; j < CT; j++) {
                if (KG > 1) atomicAdd(&out[(size_t)r * B + tx + TX * j], acc[i][j]);
                else out[(size_t)r * B + tx + TX * j] = acc[i][j];
            }
        }
    }
}

// input layer: A=1, B=16; vectorized over b-quads
static __global__ void kconv_in(float* __restrict__ out, const float* __restrict__ f,
                                const int* __restrict__ nbr, const float* __restrict__ W,
                                int N, int zr) {
    int t = blockIdx.x * blockDim.x + threadIdx.x;
    if (t >= N * 4) return;
    int n = t >> 2, bq = t & 3;
    float4 acc = make_float4(0.f, 0.f, 0.f, 0.f);
    const float4* W4 = (const float4*)W;
    for (int k = 0; k < 27; k++) {
        int id = nbr[n * 27 + k];
        if (id == zr) continue;
        float v = f[id];
        float4 w = W4[k * 4 + bq];
        acc.x = fmaf(v, w.x, acc.x);
        acc.y = fmaf(v, w.y, acc.y);
        acc.z = fmaf(v, w.z, acc.z);
        acc.w = fmaf(v, w.w, acc.w);
    }
    ((float4*)out)[n * 4 + bq] = acc;
}

// ---------------- heads / epilogue ----------------

static __global__ void kscores(float* __restrict__ sc, const float* __restrict__ x,
                               const float* __restrict__ w, int N, int C) {
    int n = blockIdx.x * blockDim.x + threadIdx.x;
    if (n >= N) return;
    float s0 = 0.0f, s1 = 0.0f;
    const float* xr = x + (size_t)n * C;
    for (int c = 0; c < C; c++) {
        float v = xr[c];
        s0 = fmaf(v, w[2 * c], s0);
        s1 = fmaf(v, w[2 * c + 1], s1);
    }
    sc[2 * n] = s0;
    sc[2 * n + 1] = s1;
}

// y has N+1 rows (row N zeroed). float4 vectorized.
static __global__ void kmulatt(float4* __restrict__ y, const float4* __restrict__ fmap,
                               const int* __restrict__ up, const float* __restrict__ sc,
                               int N, int C4) {
    int t = blockIdx.x * blockDim.x + threadIdx.x;
    if (t >= (N + 1) * C4) return;
    int n = t / C4;
    if (n >= N) { y[t] = make_float4(0.f, 0.f, 0.f, 0.f); return; }
    int p = up[n];
    float att = (sc[2 * p + 1] > sc[2 * p]) ? 1.0f : 0.0f;
    float4 q = fmap[t];
    y[t] = make_float4(q.x * att, q.y * att, q.z * att, q.w * att);
}

static __global__ void kout0(float* __restrict__ out, const float* __restrict__ z,
                             const float* __restrict__ pw, const float* __restrict__ sw,
                             int N) {
    int n = blockIdx.x * blockDim.x + threadIdx.x;
    if (n >= N) return;
    float o0 = 0, o1 = 0, o2 = 0, o3 = 0, o4 = 0;
    const float* zr = z + (size_t)n * 16;
#pragma unroll
    for (int c = 0; c < 16; c++) {
        float v = zr[c];
        o0 = fmaf(v, pw[3 * c], o0);
        o1 = fmaf(v, pw[3 * c + 1], o1);
        o2 = fmaf(v, pw[3 * c + 2], o2);
        o3 = fmaf(v, sw[2 * c], o3);
        o4 = fmaf(v, sw[2 * c + 1], o4);
    }
    float* r = out + (size_t)n * 5;
    r[0] = o0; r[1] = o1; r[2] = o2; r[3] = o3; r[4] = o4;
}

static __global__ void koutc(float* __restrict__ out, const int* __restrict__ coords,
                             const float* __restrict__ sc, int N) {
    int n = blockIdx.x * blockDim.x + threadIdx.x;
    if (n >= N) return;
    float* r = out + (size_t)n * 5;
    r[0] = (float)coords[3 * n];
    r[1] = (float)coords[3 * n + 1];
    r[2] = (float)coords[3 * n + 2];
    r[3] = sc[2 * n];
    r[4] = sc[2 * n + 1];
}

// ---------------- host-side helpers ----------------

static inline int cdiv(long a, int b) { return (int)((a + b - 1) / b); }

static void conv(hipStream_t s, float* out, const float* feat, const int* nbr,
                 const float* Wt, const float* res, int N, int A, int B, int TAPS, int zr) {
#define CASE(AA, BB, TT, TRR, TXX, KGG)                                                    \
    else if (A == AA && B == BB && TAPS == TT) {                                           \
        if (KGG > 1 && !res) hipMemsetAsync(out, 0, (size_t)N * BB * 4, s);                \
        dim3 g(cdiv(N, TRR), KGG), blk(256);                                               \
        if (res) kconv2<AA, BB, TT, TRR, TXX, KGG, true><<<g, blk, 0, s>>>(out, feat, nbr, Wt, res, N, zr); \
        else     kconv2<AA, BB, TT, TRR, TXX, KGG, false><<<g, blk, 0, s>>>(out, feat, nbr, Wt, nullptr, N, zr); \
    }
    if (false) {}
    CASE(16, 16, 27, 128, 8, 1)   // L0 sub + ppn3 (N~100k)
    CASE(32, 32, 27, 128, 8, 1)   // L1 sub (N~92k)
    CASE(48, 48, 27, 96, 8, 1)    // L2 sub + ppn2 (N~63k)
    CASE(64, 64, 27, 32, 16, 2)   // L3 sub (N~14k): 429x2=858 blocks
    CASE(80, 80, 27, 32, 16, 9)   // ppn1 @ L4 (N~1.7k): 54x9=486 blocks
    CASE(16, 32, 8, 128, 8, 1)    // down0
    CASE(32, 48, 8, 128, 8, 1)    // down1
    CASE(48, 64, 8, 32, 16, 2)    // down2: 429x2=858 blocks
    CASE(64, 80, 8, 32, 16, 4)    // down3: 54x4=216 blocks
#undef CASE
}

static void bnapply(hipStream_t s, float* out, const float* x, double* st,
                    const float* g, const float* b, int N, int C) {
    kstats<<<cdiv(N, 256), 4 * C, 8 * C * 2 * sizeof(double), s>>>(st, x, N, C);
    int quads = (N + 1) * (C / 4);
    kbnrelu<<<cdiv(quads, 256), 256, 0, s>>>((float4*)out, (const float4*)x, st, g, b, N, C);
}

extern "C" void kernel_launch(void* const* d_in, const int* in_sizes, int n_in,
                              void* d_out, int out_size, void* d_ws, size_t ws_size,
                              hipStream_t stream) {
    (void)n_in; (void)out_size; (void)ws_size;
    const int SL[5] = {192, 96, 48, 24, 12};
    const int C[5] = {16, 32, 48, 64, 80};
    int N[5];
    const int* coords[5];
    for (int l = 0; l < 5; l++) { N[l] = in_sizes[l] / 3; coords[l] = (const int*)d_in[l]; }
    const float* features = (const float*)d_in[5];
    const float* w_in = (const float*)d_in[6];
    const float *blk_w[4], *blk_g[4], *blk_b[4], *dn_g[4], *dn_b[4], *dn_w[4];
    for (int i = 0; i < 4; i++) {
        blk_w[i] = (const float*)d_in[7 + 6 * i];
        blk_g[i] = (const float*)d_in[8 + 6 * i];
        blk_b[i] = (const float*)d_in[9 + 6 * i];
        dn_g[i] = (const float*)d_in[10 + 6 * i];
        dn_b[i] = (const float*)d_in[11 + 6 * i];
        dn_w[i] = (const float*)d_in[12 + 6 * i];
    }
    const float* ppn1_w  = (const float*)d_in[31];
    const float* ppn1_sw = (const float*)d_in[32];
    const float* ppn2_w  = (const float*)d_in[33];
    const float* ppn2_sw = (const float*)d_in[34];
    const float* ppn3_w  = (const float*)d_in[35];
    const float* ppn3_pw = (const float*)d_in[36];
    const float* ppn3_sw = (const float*)d_in[37];
    float* dout = (float*)d_out;

    // ---- workspace layout ----
    char* ws = (char*)d_ws;
    size_t off = 0;
    auto alloc = [&](size_t bytes) -> char* {
        off = (off + 255) & ~(size_t)255;
        char* p = ws + off;
        off += bytes;
        return p;
    };
    int* nbr[5];
    for (int l = 0; l < 5; l++) nbr[l] = (int*)alloc((size_t)N[l] * 27 * 4);
    int* down8[4];
    for (int i = 0; i < 4; i++) down8[i] = (int*)alloc((size_t)N[i + 1] * 8 * 4);
    int* up1 = (int*)alloc((size_t)N[2] * 4);
    int* up2 = (int*)alloc((size_t)N[0] * 4);
    double* stats = (double*)alloc(26 * 160 * sizeof(double));
    float* blkWt[4];
    float* dnWt[4];
    for (int i = 0; i < 4; i++) {
        blkWt[i] = (float*)alloc((size_t)108 * C[i] * C[i] * 4);
        dnWt[i] = (float*)alloc((size_t)8 * C[i] * C[i + 1] * 4);
    }
    float* p1Wt = (float*)alloc((size_t)27 * 80 * 80 * 4);
    float* p2Wt = (float*)alloc((size_t)27 * 48 * 48 * 4);
    float* p3Wt = (float*)alloc((size_t)27 * 16 * 16 * 4);
    float* fmap0 = (float*)alloc((size_t)N[0] * 16 * 4);
    float* fmap2 = (float*)alloc((size_t)N[2] * 48 * 4);
    float* sc1 = (float*)alloc((size_t)N[4] * 2 * 4);
    float* sc2 = (float*)alloc((size_t)N[2] * 2 * 4);

    // transient region: grids (phase 1) alias the 3 rotating feature buffers (phase 2)
    size_t BIG = 0;
    for (int l = 0; l < 5; l++) {
        size_t s = (size_t)(N[l] + 1) * C[l] * 4;
        if (s > BIG) BIG = s;
    }
    BIG = (BIG + 255) & ~(size_t)255;
    off = (off + 255) & ~(size_t)255;
    size_t trans = off;
    int* grid[5];
    size_t gtot = 0;
    for (int l = 0; l < 5; l++) {
        grid[l] = (int*)(ws + trans + gtot);
        gtot += (size_t)SL[l] * SL[l] * SL[l] * 4;
    }
    float* B0 = (float*)(ws + trans);
    float* B1 = (float*)(ws + trans + BIG);
    float* B2 = (float*)(ws + trans + 2 * BIG);

    // ---- phase 1: index structures + weight transposes + stats zero ----
    hipMemsetAsync(ws + trans, 0xFF, gtot, stream);  // all grids = -1
    hipMemsetAsync(stats, 0, 26 * 160 * sizeof(double), stream);
    for (int l = 0; l < 5; l++)
        kscatter<<<cdiv(N[l], TPB), TPB, 0, stream>>>(grid[l], coords[l], N[l], SL[l]);
    for (int l = 0; l < 5; l++)
        knbr27<<<cdiv((long)N[l] * 27, TPB), TPB, 0, stream>>>(nbr[l], coords[l], grid[l], N[l], SL[l], N[l]);
    for (int i = 0; i < 4; i++)
        kdown8<<<cdiv((long)N[i + 1] * 8, TPB), TPB, 0, stream>>>(down8[i], coords[i + 1], grid[i], N[i + 1], SL[i], N[i]);
    kup<<<cdiv(N[2], TPB), TPB, 0, stream>>>(up1, coords[2], grid[4], N[2], 12);
    kup<<<cdiv(N[0], TPB), TPB, 0, stream>>>(up2, coords[0], grid[2], N[0], 48);
    for (int i = 0; i < 4; i++) {
        int n1 = 108 * C[i] * C[i];
        ktrans<<<cdiv(n1, TPB), TPB, 0, stream>>>(blkWt[i], blk_w[i], 108, C[i], C[i]);
        int n2 = 8 * C[i] * C[i + 1];
        ktrans<<<cdiv(n2, TPB), TPB, 0, stream>>>(dnWt[i], dn_w[i], 8, C[i], C[i + 1]);
    }
    ktrans<<<cdiv(27 * 6400, TPB), TPB, 0, stream>>>(p1Wt, ppn1_w, 27, 80, 80);
    ktrans<<<cdiv(27 * 2304, TPB), TPB, 0, stream>>>(p2Wt, ppn2_w, 27, 48, 48);
    ktrans<<<cdiv(27 * 256, TPB), TPB, 0, stream>>>(p3Wt, ppn3_w, 27, 16, 16);

    // ---- phase 2: network (grids dead; B0/B1/B2 alias that memory) ----
    int slot = 0;
    auto st = [&]() { return stats + 160 * (slot++); };

    float* curX = B0;
    kconv_in<<<cdiv((long)N[0] * 4, TPB), TPB, 0, stream>>>(curX, features, nbr[0], w_in, N[0], N[0]);
    hipMemcpyAsync(fmap0, curX, (size_t)N[0] * 16 * 4, hipMemcpyDeviceToDevice, stream);

    auto others = [&](float* cur, float*& t1, float*& t2) {
        if (cur == B0) { t1 = B1; t2 = B2; }
        else if (cur == B1) { t1 = B0; t2 = B2; }
        else { t1 = B0; t2 = B1; }
    };

    for (int i = 0; i < 4; i++) {
        int Ni = N[i], Ci = C[i];
        float *T1, *T2;
        others(curX, T1, T2);
        for (int r = 0; r < 2; r++) {
            const float* w0 = blkWt[i] + (size_t)(2 * r) * 27 * Ci * Ci;
            const float* w1 = blkWt[i] + (size_t)(2 * r + 1) * 27 * Ci * Ci;
            bnapply(stream, T1, curX, st(), blk_g[i] + (2 * r) * Ci, blk_b[i] + (2 * r) * Ci, Ni, Ci);
            conv(stream, T2, T1, nbr[i], w0, nullptr, Ni, Ci, Ci, 27, Ni);
            bnapply(stream, T1, T2, st(), blk_g[i] + (2 * r + 1) * Ci, blk_b[i] + (2 * r + 1) * Ci, Ni, Ci);
            conv(stream, curX, T1, nbr[i], w1, curX, Ni, Ci, Ci, 27, Ni);   // fused residual (out==res)
        }
        bnapply(stream, T1, curX, st(), dn_g[i], dn_b[i], Ni, Ci);
        conv(stream, T2, T1, down8[i], dnWt[i], nullptr, N[i + 1], Ci, C[i + 1], 8, Ni);
        if (i == 1)
            hipMemcpyAsync(fmap2, T2, (size_t)N[2] * 48 * 4, hipMemcpyDeviceToDevice, stream);
        curX = T2;
    }

    // ---- heads ----
    float *T1, *T2;
    others(curX, T1, T2);
    // curX = level-4 features; append zero row for ppn1 gather
    kzrow<<<1, 128, 0, stream>>>(curX + (size_t)N[4] * 80, 80);
    conv(stream, T1, curX, nbr[4], p1Wt, nullptr, N[4], 80, 80, 27, N[4]);
    kscores<<<cdiv(N[4], TPB), TPB, 0, stream>>>(sc1, T1, ppn1_sw, N[4], 80);
    koutc<<<cdiv(N[4], TPB), TPB, 0, stream>>>(dout + (size_t)N[0] * 5, coords[4], sc1, N[4]);
    // ppn2 @ level 2
    kmulatt<<<cdiv((long)(N[2] + 1) * 12, TPB), TPB, 0, stream>>>((float4*)T2, (const float4*)fmap2, up1, sc1, N[2], 12);
    conv(stream, curX, T2, nbr[2], p2Wt, nullptr, N[2], 48, 48, 27, N[2]);
    kscores<<<cdiv(N[2], TPB), TPB, 0, stream>>>(sc2, curX, ppn2_sw, N[2], 48);
    koutc<<<cdiv(N[2], TPB), TPB, 0, stream>>>(dout + (size_t)(N[0] + N[4]) * 5, coords[2], sc2, N[2]);
    // ppn3 @ level 0
    kmulatt<<<cdiv((long)(N[0] + 1) * 4, TPB), TPB, 0, stream>>>((float4*)T1, (const float4*)fmap0, up2, sc2, N[0], 4);
    conv(stream, T2, T1, nbr[0], p3Wt, nullptr, N[0], 16, 16, 27, N[0]);
    kout0<<<cdiv(N[0], TPB), TPB, 0, stream>>>(dout, T2, ppn3_pw, ppn3_sw, N[0]);
}